// Round 11
// baseline (589.264 us; speedup 1.0000x reference)
//
#include <hip/hip_runtime.h>
#include <hip/hip_bf16.h>

#define N_FEAT 128
#define HIDDEN 128
#define NHEAD  4
#define NHID   32
#define NCLASS 40

// ---------------- CSR build ----------------

__global__ __launch_bounds__(256) void k_zero(int* __restrict__ p, int n) {
  int i = blockIdx.x * 256 + threadIdx.x;
  if (i < n) p[i] = 0;
}

__global__ __launch_bounds__(256) void k_hist(const int* __restrict__ dst, int* __restrict__ counts, int E) {
  int e = blockIdx.x * 256 + threadIdx.x;
  if (e < E) atomicAdd(&counts[dst[e]], 1);
}

// Block-wide inclusive scan of 256 ints in LDS (Hillis-Steele).
__device__ __forceinline__ int block_incl_scan_256(int v, int* sm) {
  int t = threadIdx.x;
  sm[t] = v;
  __syncthreads();
  #pragma unroll
  for (int d = 1; d < 256; d <<= 1) {
    int u = (t >= d) ? sm[t - d] : 0;
    __syncthreads();
    sm[t] += u;
    __syncthreads();
  }
  return sm[t];
}

// Parallel 3-phase exclusive scan. Valid for N <= 65536 (N=50000 here).
__global__ __launch_bounds__(256) void k_bsum(const int* __restrict__ counts, int* __restrict__ bsum, int N) {
  __shared__ int sm[256];
  int i = blockIdx.x * 256 + threadIdx.x;
  int v = (i < N) ? counts[i] : 0;
  int incl = block_incl_scan_256(v, sm);
  if (threadIdx.x == 255) bsum[blockIdx.x] = incl;
}

__global__ __launch_bounds__(256) void k_scanb(const int* __restrict__ bsum, int* __restrict__ boff,
                                               int* __restrict__ offs, int nblk, int N) {
  __shared__ int sm[256];
  int t = threadIdx.x;
  int v = (t < nblk) ? bsum[t] : 0;
  int incl = block_incl_scan_256(v, sm);
  if (t < nblk) boff[t] = incl - v;   // exclusive
  if (t == 255) offs[N] = incl;       // grand total
}

// counts aliases cursor: each index is read-then-written by the same thread.
__global__ __launch_bounds__(256) void k_scanfin(const int* __restrict__ counts, const int* __restrict__ boff,
                                                 int* __restrict__ offs, int* __restrict__ cursor, int N) {
  __shared__ int sm[256];
  int b = blockIdx.x;
  int i = b * 256 + threadIdx.x;
  int v = (i < N) ? counts[i] : 0;
  int incl = block_incl_scan_256(v, sm);
  int excl = incl - v + boff[b];
  if (i < N) {
    offs[i] = excl;
    cursor[i] = excl;
  }
}

__global__ __launch_bounds__(256) void k_scatter(const int* __restrict__ src, const int* __restrict__ dst,
                                                 int* __restrict__ cursor, int* __restrict__ csr_src, int E) {
  int e = blockIdx.x * 256 + threadIdx.x;
  if (e < E) {
    int d = dst[e];
    int pos = atomicAdd(&cursor[d], 1);
    csr_src[pos] = src[e];
  }
}

// fp32 -> bf16 round-to-nearest-even, returned as raw bits
__device__ __forceinline__ unsigned short f2bf(float x) {
  unsigned int u = __float_as_uint(x);
  u += 0x7fffu + ((u >> 16) & 1u);
  return (unsigned short)(u >> 16);
}

// ---------------- GEMMs (fp32 vector; no fp32 MFMA on CDNA4) ----------------
// Fused attention-coefficient epilogue (es/ed from fp32 accumulators).
// H is stored ONLY as bf16 (sole consumer is the k_agg gather; es/ed are
// computed here from fp32) -> halves gather AND write bytes.

// Hb16[N,128](bf16) = X[N,128] @ W[128,128]; 32-row tile, 4x4 register blocking
__global__ __launch_bounds__(256) void k_gemm128(const float* __restrict__ X, const float* __restrict__ W,
                                                 const float* __restrict__ a_s, const float* __restrict__ a_d,
                                                 unsigned short* __restrict__ Hb16, float* __restrict__ es,
                                                 float* __restrict__ ed, int N) {
  __shared__ float xs[32][132];   // row stride 528B = 33*16B -> float4-aligned
  int row0 = blockIdx.x * 32;
  int tid = threadIdx.x;
  for (int i = tid; i < 1024; i += 256) {
    int r = i >> 5, c4 = i & 31;
    int row = row0 + r;
    float4 v = make_float4(0.f, 0.f, 0.f, 0.f);
    if (row < N) v = *reinterpret_cast<const float4*>(X + (size_t)row * 128 + c4 * 4);
    *reinterpret_cast<float4*>(&xs[r][c4 * 4]) = v;
  }
  __syncthreads();
  int tc = tid & 31;   // cols 4*tc..4*tc+3
  int tr = tid >> 5;   // rows tr, tr+8, tr+16, tr+24
  float acc[4][4] = {};
  const float* Wp = W + tc * 4;
  #pragma unroll 4
  for (int k = 0; k < 128; ++k) {
    float4 w = *reinterpret_cast<const float4*>(Wp + (size_t)k * 128);
    float x0 = xs[tr][k], x1 = xs[tr + 8][k], x2 = xs[tr + 16][k], x3 = xs[tr + 24][k];
    acc[0][0] += x0 * w.x; acc[0][1] += x0 * w.y; acc[0][2] += x0 * w.z; acc[0][3] += x0 * w.w;
    acc[1][0] += x1 * w.x; acc[1][1] += x1 * w.y; acc[1][2] += x1 * w.z; acc[1][3] += x1 * w.w;
    acc[2][0] += x2 * w.x; acc[2][1] += x2 * w.y; acc[2][2] += x2 * w.z; acc[2][3] += x2 * w.w;
    acc[3][0] += x3 * w.x; acc[3][1] += x3 * w.y; acc[3][2] += x3 * w.z; acc[3][3] += x3 * w.w;
  }
  #pragma unroll
  for (int m = 0; m < 4; ++m) {
    int row = row0 + tr + 8 * m;
    if (row < N) {
      ushort4 b = make_ushort4(f2bf(acc[m][0]), f2bf(acc[m][1]), f2bf(acc[m][2]), f2bf(acc[m][3]));
      *reinterpret_cast<ushort4*>(Hb16 + (size_t)row * 128 + tc * 4) = b;  // 8B aligned
    }
  }
  // ---- fused coef epilogue (fp32 acc; unchanged numerics) ----
  __syncthreads();   // all k-loop reads of xs done
  #pragma unroll
  for (int m = 0; m < 4; ++m)
    *reinterpret_cast<float4*>(&xs[tr + 8 * m][tc * 4]) =
        make_float4(acc[m][0], acc[m][1], acc[m][2], acc[m][3]);
  __syncthreads();
  if (tid < 128) {
    int r = tid >> 2, hd = tid & 3;           // 32 rows x 4 heads
    int row = row0 + r;
    if (row < N) {
      const float* asp = a_s + hd * NHID;
      const float* adp = a_d + hd * NHID;
      float s1 = 0.f, s2 = 0.f;
      #pragma unroll
      for (int c = 0; c < NHID; ++c) {
        float v = xs[r][hd * NHID + c];
        s1 += v * asp[c];
        s2 += v * adp[c];
      }
      es[row * NHEAD + hd] = s1;
      ed[row * NHEAD + hd] = s2;
    }
  }
}

// Hb16[N,40](bf16) = X[N,128] @ W[128,40]; fused single-head coef epilogue.
// (final accumulate + d_out stay fp32 in k_agg)
__global__ __launch_bounds__(256) void k_gemm40(const float* __restrict__ X, const float* __restrict__ W,
                                                const float* __restrict__ a_s, const float* __restrict__ a_d,
                                                unsigned short* __restrict__ Hb16, float* __restrict__ es,
                                                float* __restrict__ ed, int N) {
  __shared__ float xs[32][132];
  __shared__ float ws[128 * 40];
  int row0 = blockIdx.x * 32;
  int tid = threadIdx.x;
  for (int i = tid; i < 1024; i += 256) {
    int r = i >> 5, c4 = i & 31;
    int row = row0 + r;
    float4 v = make_float4(0.f, 0.f, 0.f, 0.f);
    if (row < N) v = *reinterpret_cast<const float4*>(X + (size_t)row * 128 + c4 * 4);
    *reinterpret_cast<float4*>(&xs[r][c4 * 4]) = v;
  }
  for (int i = tid; i < 1280; i += 256)
    *reinterpret_cast<float4*>(&ws[i * 4]) = *reinterpret_cast<const float4*>(W + i * 4);
  __syncthreads();
  int r = tid >> 3;   // 32 rows
  int cg = tid & 7;   // 8 groups * 5 cols
  float acc[5] = {};
  #pragma unroll 4
  for (int k = 0; k < 128; ++k) {
    float xv = xs[r][k];
    #pragma unroll
    for (int j = 0; j < 5; ++j) acc[j] += xv * ws[k * 40 + cg * 5 + j];
  }
  int row = row0 + r;
  if (row < N) {
    #pragma unroll
    for (int j = 0; j < 5; ++j) Hb16[(size_t)row * 40 + cg * 5 + j] = f2bf(acc[j]);
  }
  // ---- fused coef epilogue (1 head, 40 channels; fp32) ----
  __syncthreads();   // k-loop reads of xs done
  #pragma unroll
  for (int j = 0; j < 5; ++j) xs[r][cg * 5 + j] = acc[j];
  __syncthreads();
  if (tid < 32) {
    int rr = tid;
    int rw = row0 + rr;
    if (rw < N) {
      float s1 = 0.f, s2 = 0.f;
      #pragma unroll
      for (int c = 0; c < NCLASS; ++c) {
        float v = xs[rr][c];
        s1 += v * a_s[c];
        s2 += v * a_d[c];
      }
      es[rw] = s1;
      ed[rw] = s2;
    }
  }
}

// ---------------- dst-centric aggregation (one wave per node) ----------------
// Lane handles adjacent channel pair (2*lane, 2*lane+1) -> same head always.
// Edge loop unrolled x16 (avg degree ~17: one group covers most lists).
// 32-bit unsigned offsets (s*CTOT+c <= 6.4M) -> saddr + voffset addressing,
// cutting per-gather VALU vs 64-bit chains. All gathers bf16 (4B/lane/edge).

__device__ __forceinline__ float lrelu02(float x) { return x > 0.f ? x : 0.2f * x; }

// MODE 0: out = elu(agg + b)          (layer 0)
// MODE 1: out = elu(agg + b + x_in)   (hidden layers, residual; in-place safe)
// MODE 2: out = agg + b               (output layer)
template <int CTOT, int HEADS, int MODE>
__global__ __launch_bounds__(256) void k_agg(const unsigned short* __restrict__ hb, const float* __restrict__ es,
                                             const float* __restrict__ ed, const int* __restrict__ offs,
                                             const int* __restrict__ csr_src, const float* __restrict__ bias,
                                             const float* __restrict__ x_in, float* __restrict__ out, int N) {
  int wid = (blockIdx.x * 256 + threadIdx.x) >> 6;
  int lane = threadIdx.x & 63;
  if (wid >= N) return;
  constexpr int CH = CTOT / HEADS;
  constexpr int PAIRS = CTOT / 2;   // 64 for CTOT=128, 20 for CTOT=40
  int n = wid;
  int c = 2 * lane;
  bool act = lane < PAIRS;
  int hd = act ? (c / CH) : 0;
  float edv = ed[n * HEADS + hd];
  float acc0 = 0.f, acc1 = 0.f, sp = 0.f;
  int beg = offs[n], end = offs[n + 1];
  // softmax-max subtraction skipped: alpha = p/s is shift-invariant, logits bounded
  int i = beg;
  for (; i + 16 <= end; i += 16) {
    int sA[16];
    #pragma unroll
    for (int u = 0; u < 16; ++u) sA[u] = csr_src[i + u];
    float eA[16];
    #pragma unroll
    for (int u = 0; u < 16; ++u) eA[u] = es[(unsigned)(sA[u] * HEADS + hd)];
    float hx[16], hy[16];
    #pragma unroll
    for (int u = 0; u < 16; ++u) {
      unsigned off = (unsigned)sA[u] * (unsigned)CTOT + (unsigned)c;
      unsigned int v = act ? *reinterpret_cast<const unsigned int*>(hb + off) : 0u;
      hx[u] = __uint_as_float(v << 16);
      hy[u] = __uint_as_float(v & 0xffff0000u);
    }
    #pragma unroll
    for (int u = 0; u < 16; ++u) {
      float p = __expf(lrelu02(eA[u] + edv));
      sp += p;
      acc0 += p * hx[u];
      acc1 += p * hy[u];
    }
  }
  for (; i <= end; ++i) {          // tail (<16 edges) + self-loop at i == end
    int s = (i < end) ? csr_src[i] : n;
    float p = __expf(lrelu02(es[(unsigned)(s * HEADS + hd)] + edv));
    sp += p;
    if (act) {
      unsigned off = (unsigned)s * (unsigned)CTOT + (unsigned)c;
      unsigned int v = *reinterpret_cast<const unsigned int*>(hb + off);
      acc0 += p * __uint_as_float(v << 16);
      acc1 += p * __uint_as_float(v & 0xffff0000u);
    }
  }
  if (act) {
    float v0 = acc0 / sp + bias[c];
    float v1 = acc1 / sp + bias[c + 1];
    if (MODE == 1) {
      float2 xv = *reinterpret_cast<const float2*>(x_in + (size_t)n * CTOT + c);
      v0 += xv.x;
      v1 += xv.y;
    }
    if (MODE != 2) {
      v0 = v0 > 0.f ? v0 : __expf(v0) - 1.f;
      v1 = v1 > 0.f ? v1 : __expf(v1) - 1.f;
    }
    *reinterpret_cast<float2*>(out + (size_t)n * CTOT + c) = make_float2(v0, v1);
  }
}

// ---------------- launch ----------------

extern "C" void kernel_launch(void* const* d_in, const int* in_sizes, int n_in,
                              void* d_out, int out_size, void* d_ws, size_t ws_size,
                              hipStream_t stream) {
  const float* X   = (const float*)d_in[0];
  const int*   EI  = (const int*)d_in[1];
  const float* W0  = (const float*)d_in[2];
  const float* AS0 = (const float*)d_in[3];
  const float* AD0 = (const float*)d_in[4];
  const float* B0  = (const float*)d_in[5];
  const float* W1  = (const float*)d_in[6];
  const float* AS1 = (const float*)d_in[7];
  const float* AD1 = (const float*)d_in[8];
  const float* B1  = (const float*)d_in[9];
  const float* W2  = (const float*)d_in[10];
  const float* AS2 = (const float*)d_in[11];
  const float* AD2 = (const float*)d_in[12];
  const float* B2  = (const float*)d_in[13];
  const float* WO  = (const float*)d_in[14];
  const float* ASO = (const float*)d_in[15];
  const float* ADO = (const float*)d_in[16];
  const float* BO  = (const float*)d_in[17];

  int N = in_sizes[0] / N_FEAT;   // 50000
  int E = in_sizes[1] / 2;        // 800000
  const int* srcv = EI;
  const int* dstv = EI + E;

  char* w = (char*)d_ws;
  auto alloc = [&](size_t bytes) {
    char* p = w;
    w += (bytes + 255) & ~(size_t)255;
    return p;
  };
  int*            offs    = (int*)alloc((size_t)(N + 1) * sizeof(int));
  int*            cursor  = (int*)alloc((size_t)N * sizeof(int));   // doubles as counts
  int*            csr_src = (int*)alloc((size_t)E * sizeof(int));
  float*          es      = (float*)alloc((size_t)N * NHEAD * sizeof(float));
  float*          ed      = (float*)alloc((size_t)N * NHEAD * sizeof(float));
  float*          xb      = (float*)alloc((size_t)N * HIDDEN * sizeof(float));
  unsigned short* hb16    = (unsigned short*)alloc((size_t)N * HIDDEN * sizeof(unsigned short));
  unsigned short* ho16    = (unsigned short*)alloc((size_t)N * NCLASS * sizeof(unsigned short));
  int*            bsum    = (int*)alloc(256 * sizeof(int));
  int*            boff    = (int*)alloc(256 * sizeof(int));
  (void)ws_size;

  int egrid = (E + 255) / 256;
  int ngrid = (N + 255) / 256;
  int ggrid = (N + 31) / 32;
  int agrid = (N + 3) / 4;   // 4 waves (nodes) per 256-thread block
  int sblk  = (N + 255) / 256;   // scan blocks (196 <= 256)

  // CSR build (edge list is input-only; ws is re-poisoned every call, so rebuild)
  k_zero<<<ngrid, 256, 0, stream>>>(cursor, N);
  k_hist<<<egrid, 256, 0, stream>>>(dstv, cursor, E);
  k_bsum<<<sblk, 256, 0, stream>>>(cursor, bsum, N);
  k_scanb<<<1, 256, 0, stream>>>(bsum, boff, offs, sblk, N);
  k_scanfin<<<sblk, 256, 0, stream>>>(cursor, boff, offs, cursor, N);
  k_scatter<<<egrid, 256, 0, stream>>>(srcv, dstv, cursor, csr_src, E);

  // layer 0
  k_gemm128<<<ggrid, 256, 0, stream>>>(X, W0, AS0, AD0, hb16, es, ed, N);
  k_agg<HIDDEN, NHEAD, 0><<<agrid, 256, 0, stream>>>(hb16, es, ed, offs, csr_src, B0, nullptr, xb, N);
  // layer 1
  k_gemm128<<<ggrid, 256, 0, stream>>>(xb, W1, AS1, AD1, hb16, es, ed, N);
  k_agg<HIDDEN, NHEAD, 1><<<agrid, 256, 0, stream>>>(hb16, es, ed, offs, csr_src, B1, xb, xb, N);
  // layer 2
  k_gemm128<<<ggrid, 256, 0, stream>>>(xb, W2, AS2, AD2, hb16, es, ed, N);
  k_agg<HIDDEN, NHEAD, 1><<<agrid, 256, 0, stream>>>(hb16, es, ed, offs, csr_src, B2, xb, xb, N);
  // output layer (bf16 gather; accumulate + d_out fp32)
  k_gemm40<<<ggrid, 256, 0, stream>>>(xb, WO, ASO, ADO, ho16, es, ed, N);
  k_agg<NCLASS, 1, 2><<<agrid, 256, 0, stream>>>(ho16, es, ed, offs, csr_src, BO, nullptr, (float*)d_out, N);
}

// Round 12
// 482.463 us; speedup vs baseline: 1.2214x; 1.2214x over previous
//
#include <hip/hip_runtime.h>
#include <hip/hip_bf16.h>

#define N_FEAT 128
#define HIDDEN 128
#define NHEAD  4
#define NHID   32
#define NCLASS 40

typedef __attribute__((ext_vector_type(8))) short short8v;   // 8 bf16 (4 VGPR)
typedef __attribute__((ext_vector_type(4))) float float4v;   // 4 fp32 acc

// ---------------- CSR build ----------------

__global__ __launch_bounds__(256) void k_zero(int* __restrict__ p, int n) {
  int i = blockIdx.x * 256 + threadIdx.x;
  if (i < n) p[i] = 0;
}

__global__ __launch_bounds__(256) void k_hist(const int* __restrict__ dst, int* __restrict__ counts, int E) {
  int e = blockIdx.x * 256 + threadIdx.x;
  if (e < E) atomicAdd(&counts[dst[e]], 1);
}

// Block-wide inclusive scan of 256 ints in LDS (Hillis-Steele).
__device__ __forceinline__ int block_incl_scan_256(int v, int* sm) {
  int t = threadIdx.x;
  sm[t] = v;
  __syncthreads();
  #pragma unroll
  for (int d = 1; d < 256; d <<= 1) {
    int u = (t >= d) ? sm[t - d] : 0;
    __syncthreads();
    sm[t] += u;
    __syncthreads();
  }
  return sm[t];
}

// Parallel 3-phase exclusive scan. Valid for N <= 65536 (N=50000 here).
__global__ __launch_bounds__(256) void k_bsum(const int* __restrict__ counts, int* __restrict__ bsum, int N) {
  __shared__ int sm[256];
  int i = blockIdx.x * 256 + threadIdx.x;
  int v = (i < N) ? counts[i] : 0;
  int incl = block_incl_scan_256(v, sm);
  if (threadIdx.x == 255) bsum[blockIdx.x] = incl;
}

__global__ __launch_bounds__(256) void k_scanb(const int* __restrict__ bsum, int* __restrict__ boff,
                                               int* __restrict__ offs, int nblk, int N) {
  __shared__ int sm[256];
  int t = threadIdx.x;
  int v = (t < nblk) ? bsum[t] : 0;
  int incl = block_incl_scan_256(v, sm);
  if (t < nblk) boff[t] = incl - v;   // exclusive
  if (t == 255) offs[N] = incl;       // grand total
}

// counts aliases cursor: each index is read-then-written by the same thread.
__global__ __launch_bounds__(256) void k_scanfin(const int* __restrict__ counts, const int* __restrict__ boff,
                                                 int* __restrict__ offs, int* __restrict__ cursor, int N) {
  __shared__ int sm[256];
  int b = blockIdx.x;
  int i = b * 256 + threadIdx.x;
  int v = (i < N) ? counts[i] : 0;
  int incl = block_incl_scan_256(v, sm);
  int excl = incl - v + boff[b];
  if (i < N) {
    offs[i] = excl;
    cursor[i] = excl;
  }
}

__global__ __launch_bounds__(256) void k_scatter(const int* __restrict__ src, const int* __restrict__ dst,
                                                 int* __restrict__ cursor, int* __restrict__ csr_src, int E) {
  int e = blockIdx.x * 256 + threadIdx.x;
  if (e < E) {
    int d = dst[e];
    int pos = atomicAdd(&cursor[d], 1);
    csr_src[pos] = src[e];
  }
}

// fp32 -> bf16 round-to-nearest-even, returned as raw bits
__device__ __forceinline__ unsigned short f2bf(float x) {
  unsigned int u = __float_as_uint(x);
  u += 0x7fffu + ((u >> 16) & 1u);
  return (unsigned short)(u >> 16);
}
__device__ __forceinline__ float bf2f(unsigned short b) {
  return __uint_as_float(((unsigned int)b) << 16);
}

// ---------------- MFMA GEMM 128x128 (bf16 in, fp32 acc) ----------------
// Round-11 budget arithmetic: fp32 gemm128 was ~70-90us each (never in top-5
// but dominates the unaccounted time). MFMA path: stage X-tile (64x128) and
// W^T (128x128) as bf16 in LDS (+8-elem pad -> 2-way-free b128 reads),
// mfma_f32_16x16x32_bf16, 4 waves x 16 rows. C/D mapping (HW-verified):
// col=lane&15, row=(lane>>4)*4+reg. A: lane reads A[l&15][(l>>4)*8+i]
// contiguous; B from W^T rows likewise. H staged back through xa (each wave
// touches only its own rows; a-frags are in regs before overwrite) for
// coalesced bf16 stores + fused es/ed epilogue.
__global__ __launch_bounds__(256) void k_gemm128(const float* __restrict__ X, const float* __restrict__ W,
                                                 const float* __restrict__ a_s, const float* __restrict__ a_d,
                                                 unsigned short* __restrict__ Hb16, float* __restrict__ es,
                                                 float* __restrict__ ed, int N) {
  __shared__ unsigned short xa[64][136];   // X tile bf16; later H tile
  __shared__ unsigned short wt[128][136];  // W^T bf16
  int row0 = blockIdx.x * 64;
  int tid = threadIdx.x;
  // stage X (64 rows x 128 cols = 2048 float4)
  #pragma unroll
  for (int i = 0; i < 8; ++i) {
    int idx = i * 256 + tid;
    int r = idx >> 5, c4 = idx & 31;
    int row = row0 + r;
    float4 v = make_float4(0.f, 0.f, 0.f, 0.f);
    if (row < N) v = *reinterpret_cast<const float4*>(X + (size_t)row * 128 + c4 * 4);
    ushort4 b = make_ushort4(f2bf(v.x), f2bf(v.y), f2bf(v.z), f2bf(v.w));
    *reinterpret_cast<ushort4*>(&xa[r][c4 * 4]) = b;
  }
  // stage W^T (128 k x 32 j4 = 4096 float4)
  #pragma unroll
  for (int i = 0; i < 16; ++i) {
    int idx = i * 256 + tid;
    int k = idx & 127, j4 = idx >> 7;
    float4 v = *reinterpret_cast<const float4*>(W + (size_t)k * 128 + j4 * 4);
    wt[j4 * 4 + 0][k] = f2bf(v.x);
    wt[j4 * 4 + 1][k] = f2bf(v.y);
    wt[j4 * 4 + 2][k] = f2bf(v.z);
    wt[j4 * 4 + 3][k] = f2bf(v.w);
  }
  __syncthreads();
  int l = tid & 63, wv = tid >> 6;
  int lrow = l & 15, lk = l >> 4;   // lk in 0..3
  // A fragments for this wave's 16 rows (k-contiguous 16B -> ds_read_b128)
  short8v a[4];
  #pragma unroll
  for (int kk = 0; kk < 4; ++kk)
    a[kk] = *reinterpret_cast<const short8v*>(&xa[wv * 16 + lrow][kk * 32 + lk * 8]);
  // 8 column tiles of 16
  #pragma unroll
  for (int ct = 0; ct < 8; ++ct) {
    float4v acc = {0.f, 0.f, 0.f, 0.f};
    #pragma unroll
    for (int kk = 0; kk < 4; ++kk) {
      short8v b = *reinterpret_cast<const short8v*>(&wt[ct * 16 + lrow][kk * 32 + lk * 8]);
      acc = __builtin_amdgcn_mfma_f32_16x16x32_bf16(a[kk], b, acc, 0, 0, 0);
    }
    #pragma unroll
    for (int r = 0; r < 4; ++r)
      xa[wv * 16 + lk * 4 + r][ct * 16 + lrow] = f2bf(acc[r]);  // own rows only
  }
  __syncthreads();
  // coalesced H store from xa
  #pragma unroll
  for (int i = 0; i < 8; ++i) {
    int idx = i * 256 + tid;
    int r = idx >> 5, c4 = idx & 31;
    int row = row0 + r;
    if (row < N)
      *reinterpret_cast<ushort4*>(Hb16 + (size_t)row * 128 + c4 * 4) =
          *reinterpret_cast<const ushort4*>(&xa[r][c4 * 4]);
  }
  // fused coef epilogue: 64 rows x 4 heads = 256 threads
  {
    int r = tid >> 2, hd = tid & 3;
    int row = row0 + r;
    if (row < N) {
      const float* asp = a_s + hd * NHID;
      const float* adp = a_d + hd * NHID;
      float s1 = 0.f, s2 = 0.f;
      #pragma unroll
      for (int c = 0; c < NHID; ++c) {
        float v = bf2f(xa[r][hd * NHID + c]);
        s1 += v * asp[c];
        s2 += v * adp[c];
      }
      es[row * NHEAD + hd] = s1;
      ed[row * NHEAD + hd] = s2;
    }
  }
}

// Hb16[N,40](bf16) = X[N,128] @ W[128,40]; fused single-head coef epilogue.
// (final accumulate + d_out stay fp32 in k_agg)
__global__ __launch_bounds__(256) void k_gemm40(const float* __restrict__ X, const float* __restrict__ W,
                                                const float* __restrict__ a_s, const float* __restrict__ a_d,
                                                unsigned short* __restrict__ Hb16, float* __restrict__ es,
                                                float* __restrict__ ed, int N) {
  __shared__ float xs[32][132];
  __shared__ float ws[128 * 40];
  int row0 = blockIdx.x * 32;
  int tid = threadIdx.x;
  for (int i = tid; i < 1024; i += 256) {
    int r = i >> 5, c4 = i & 31;
    int row = row0 + r;
    float4 v = make_float4(0.f, 0.f, 0.f, 0.f);
    if (row < N) v = *reinterpret_cast<const float4*>(X + (size_t)row * 128 + c4 * 4);
    *reinterpret_cast<float4*>(&xs[r][c4 * 4]) = v;
  }
  for (int i = tid; i < 1280; i += 256)
    *reinterpret_cast<float4*>(&ws[i * 4]) = *reinterpret_cast<const float4*>(W + i * 4);
  __syncthreads();
  int r = tid >> 3;   // 32 rows
  int cg = tid & 7;   // 8 groups * 5 cols
  float acc[5] = {};
  #pragma unroll 4
  for (int k = 0; k < 128; ++k) {
    float xv = xs[r][k];
    #pragma unroll
    for (int j = 0; j < 5; ++j) acc[j] += xv * ws[k * 40 + cg * 5 + j];
  }
  int row = row0 + r;
  if (row < N) {
    #pragma unroll
    for (int j = 0; j < 5; ++j) Hb16[(size_t)row * 40 + cg * 5 + j] = f2bf(acc[j]);
  }
  // ---- fused coef epilogue (1 head, 40 channels; fp32) ----
  __syncthreads();   // k-loop reads of xs done
  #pragma unroll
  for (int j = 0; j < 5; ++j) xs[r][cg * 5 + j] = acc[j];
  __syncthreads();
  if (tid < 32) {
    int rr = tid;
    int rw = row0 + rr;
    if (rw < N) {
      float s1 = 0.f, s2 = 0.f;
      #pragma unroll
      for (int c = 0; c < NCLASS; ++c) {
        float v = xs[rr][c];
        s1 += v * a_s[c];
        s2 += v * a_d[c];
      }
      es[rw] = s1;
      ed[rw] = s2;
    }
  }
}

// ---------------- dst-centric aggregation (one wave per node) ----------------
// Round-10 proven version: lane owns channel pair (2*lane, 2*lane+1) -> same
// head; edge loop unrolled x8 (deg~Poisson(16): unroll-16 regressed, 45% of
// nodes fell in the serial tail). bf16 gather = 4B/lane/edge.

__device__ __forceinline__ float lrelu02(float x) { return x > 0.f ? x : 0.2f * x; }

// MODE 0: out = elu(agg + b)          (layer 0)
// MODE 1: out = elu(agg + b + x_in)   (hidden layers, residual; in-place safe)
// MODE 2: out = agg + b               (output layer)
template <int CTOT, int HEADS, int MODE, bool BF16>
__global__ __launch_bounds__(256) void k_agg(const void* __restrict__ hv, const float* __restrict__ es,
                                             const float* __restrict__ ed, const int* __restrict__ offs,
                                             const int* __restrict__ csr_src, const float* __restrict__ bias,
                                             const float* __restrict__ x_in, float* __restrict__ out, int N) {
  int wid = (blockIdx.x * 256 + threadIdx.x) >> 6;
  int lane = threadIdx.x & 63;
  if (wid >= N) return;
  constexpr int CH = CTOT / HEADS;
  constexpr int PAIRS = CTOT / 2;   // 64 for CTOT=128, 20 for CTOT=40
  const float* hf = (const float*)hv;
  const unsigned short* hb = (const unsigned short*)hv;
  int n = wid;
  int c = 2 * lane;
  bool act = lane < PAIRS;
  int hd = act ? (c / CH) : 0;
  float edv = ed[n * HEADS + hd];
  float acc0 = 0.f, acc1 = 0.f, sp = 0.f;
  int beg = offs[n], end = offs[n + 1];
  // softmax-max subtraction skipped: alpha = p/s is shift-invariant, logits bounded
  int i = beg;
  for (; i + 8 <= end; i += 8) {
    int sA[8];
    #pragma unroll
    for (int u = 0; u < 8; ++u) sA[u] = csr_src[i + u];
    float eA[8];
    #pragma unroll
    for (int u = 0; u < 8; ++u) eA[u] = es[sA[u] * HEADS + hd];
    float hx[8], hy[8];
    if (BF16) {
      #pragma unroll
      for (int u = 0; u < 8; ++u) {
        unsigned int v = act ? *reinterpret_cast<const unsigned int*>(hb + (size_t)sA[u] * CTOT + c) : 0u;
        hx[u] = __uint_as_float(v << 16);
        hy[u] = __uint_as_float(v & 0xffff0000u);
      }
    } else {
      #pragma unroll
      for (int u = 0; u < 8; ++u) {
        float2 t = act ? *reinterpret_cast<const float2*>(hf + (size_t)sA[u] * CTOT + c)
                       : make_float2(0.f, 0.f);
        hx[u] = t.x;
        hy[u] = t.y;
      }
    }
    #pragma unroll
    for (int u = 0; u < 8; ++u) {
      float p = __expf(lrelu02(eA[u] + edv));
      sp += p;
      acc0 += p * hx[u];
      acc1 += p * hy[u];
    }
  }
  for (; i <= end; ++i) {          // tail (<8 edges) + self-loop at i == end
    int s = (i < end) ? csr_src[i] : n;
    float p = __expf(lrelu02(es[s * HEADS + hd] + edv));
    sp += p;
    if (act) {
      float vx, vy;
      if (BF16) {
        unsigned int v = *reinterpret_cast<const unsigned int*>(hb + (size_t)s * CTOT + c);
        vx = __uint_as_float(v << 16);
        vy = __uint_as_float(v & 0xffff0000u);
      } else {
        float2 t = *reinterpret_cast<const float2*>(hf + (size_t)s * CTOT + c);
        vx = t.x;
        vy = t.y;
      }
      acc0 += p * vx;
      acc1 += p * vy;
    }
  }
  if (act) {
    float v0 = acc0 / sp + bias[c];
    float v1 = acc1 / sp + bias[c + 1];
    if (MODE == 1) {
      float2 xv = *reinterpret_cast<const float2*>(x_in + (size_t)n * CTOT + c);
      v0 += xv.x;
      v1 += xv.y;
    }
    if (MODE != 2) {
      v0 = v0 > 0.f ? v0 : __expf(v0) - 1.f;
      v1 = v1 > 0.f ? v1 : __expf(v1) - 1.f;
    }
    *reinterpret_cast<float2*>(out + (size_t)n * CTOT + c) = make_float2(v0, v1);
  }
}

// ---------------- launch ----------------

extern "C" void kernel_launch(void* const* d_in, const int* in_sizes, int n_in,
                              void* d_out, int out_size, void* d_ws, size_t ws_size,
                              hipStream_t stream) {
  const float* X   = (const float*)d_in[0];
  const int*   EI  = (const int*)d_in[1];
  const float* W0  = (const float*)d_in[2];
  const float* AS0 = (const float*)d_in[3];
  const float* AD0 = (const float*)d_in[4];
  const float* B0  = (const float*)d_in[5];
  const float* W1  = (const float*)d_in[6];
  const float* AS1 = (const float*)d_in[7];
  const float* AD1 = (const float*)d_in[8];
  const float* B1  = (const float*)d_in[9];
  const float* W2  = (const float*)d_in[10];
  const float* AS2 = (const float*)d_in[11];
  const float* AD2 = (const float*)d_in[12];
  const float* B2  = (const float*)d_in[13];
  const float* WO  = (const float*)d_in[14];
  const float* ASO = (const float*)d_in[15];
  const float* ADO = (const float*)d_in[16];
  const float* BO  = (const float*)d_in[17];

  int N = in_sizes[0] / N_FEAT;   // 50000
  int E = in_sizes[1] / 2;        // 800000
  const int* srcv = EI;
  const int* dstv = EI + E;

  char* w = (char*)d_ws;
  auto alloc = [&](size_t bytes) {
    char* p = w;
    w += (bytes + 255) & ~(size_t)255;
    return p;
  };
  int*            offs    = (int*)alloc((size_t)(N + 1) * sizeof(int));
  int*            cursor  = (int*)alloc((size_t)N * sizeof(int));   // doubles as counts
  int*            csr_src = (int*)alloc((size_t)E * sizeof(int));
  float*          es      = (float*)alloc((size_t)N * NHEAD * sizeof(float));
  float*          ed      = (float*)alloc((size_t)N * NHEAD * sizeof(float));
  float*          xb      = (float*)alloc((size_t)N * HIDDEN * sizeof(float));
  unsigned short* hb16    = (unsigned short*)alloc((size_t)N * HIDDEN * sizeof(unsigned short));
  unsigned short* ho16    = (unsigned short*)alloc((size_t)N * NCLASS * sizeof(unsigned short));
  int*            bsum    = (int*)alloc(256 * sizeof(int));
  int*            boff    = (int*)alloc(256 * sizeof(int));
  (void)ws_size;

  int egrid = (E + 255) / 256;
  int ngrid = (N + 255) / 256;
  int ggrid = (N + 63) / 64;     // MFMA gemm128: 64-row tiles
  int g40   = (N + 31) / 32;     // gemm40: 32-row tiles
  int agrid = (N + 3) / 4;       // 4 waves (nodes) per 256-thread block
  int sblk  = (N + 255) / 256;   // scan blocks (196 <= 256)

  // CSR build (edge list is input-only; ws is re-poisoned every call, so rebuild)
  k_zero<<<ngrid, 256, 0, stream>>>(cursor, N);
  k_hist<<<egrid, 256, 0, stream>>>(dstv, cursor, E);
  k_bsum<<<sblk, 256, 0, stream>>>(cursor, bsum, N);
  k_scanb<<<1, 256, 0, stream>>>(bsum, boff, offs, sblk, N);
  k_scanfin<<<sblk, 256, 0, stream>>>(cursor, boff, offs, cursor, N);
  k_scatter<<<egrid, 256, 0, stream>>>(srcv, dstv, cursor, csr_src, E);

  // layer 0
  k_gemm128<<<ggrid, 256, 0, stream>>>(X, W0, AS0, AD0, hb16, es, ed, N);
  k_agg<HIDDEN, NHEAD, 0, true><<<agrid, 256, 0, stream>>>(hb16, es, ed, offs, csr_src, B0, nullptr, xb, N);
  // layer 1
  k_gemm128<<<ggrid, 256, 0, stream>>>(xb, W1, AS1, AD1, hb16, es, ed, N);
  k_agg<HIDDEN, NHEAD, 1, true><<<agrid, 256, 0, stream>>>(hb16, es, ed, offs, csr_src, B1, xb, xb, N);
  // layer 2
  k_gemm128<<<ggrid, 256, 0, stream>>>(xb, W2, AS2, AD2, hb16, es, ed, N);
  k_agg<HIDDEN, NHEAD, 1, true><<<agrid, 256, 0, stream>>>(hb16, es, ed, offs, csr_src, B2, xb, xb, N);
  // output layer (bf16 gather; accumulate + d_out fp32)
  k_gemm40<<<g40, 256, 0, stream>>>(xb, WO, ASO, ADO, ho16, es, ed, N);
  k_agg<NCLASS, 1, 2, true><<<agrid, 256, 0, stream>>>(ho16, es, ed, offs, csr_src, BO, nullptr, (float*)d_out, N);
}